// Round 5
// baseline (262.388 us; speedup 1.0000x reference)
//
#include <hip/hip_runtime.h>
#include <stdint.h>

#define BB 128
#define NN 32768
#define CI 6
#define TOPK 400
#define KEEPK 200
#define CAND 1024
#define NTA 1024
#define NTB 512
#define HALF 16384
#define TILE 2048   // rows per staging tile

// ---------------- Kernel A: per-half-image top-400 (full GPU) --------------
// 256 blocks = 2 per image. Stage pred in LDS (coalesced float4, double-
// buffered), extract conf scores -> keys (bit pattern of positive float is
// order-isomorphic). Find T with count(>=T) in [400,1024] by bit-descend
// (no atomics), gather, 1024-bitonic sort desc, write top-400 composites.
__global__ __launch_bounds__(NTA) void half_select_kernel(
        const float* __restrict__ pred, unsigned long long* __restrict__ ws) {
    const int blk = blockIdx.x;
    const int b = blk >> 1, h = blk & 1;
    const int tid = threadIdx.x, lane = tid & 63, wid = tid >> 6;
    const float* img = pred + (size_t)b * (NN * CI);
    const int rbase = h * HALF;

    __shared__ float tilebuf[2][TILE * CI];        // 2 x 48 KB
    __shared__ unsigned long long cbuf[CAND];      // 8 KB
    __shared__ unsigned int redbuf[16];
    __shared__ unsigned int sh_cnt, ccount;

    uint32_t kreg[16];

    // prologue: issue tile 0 loads
    float4 r0, r1, r2;
    {
        const float4* src = (const float4*)(img + (size_t)rbase * CI);
        r0 = src[tid]; r1 = src[tid + NTA]; r2 = src[tid + 2 * NTA];
    }
    for (int tno = 0; tno < 8; ++tno) {
        float4* dst = (float4*)tilebuf[tno & 1];
        dst[tid] = r0; dst[tid + NTA] = r1; dst[tid + 2 * NTA] = r2;
        if (tno < 7) {      // issue next tile's loads; latency overlaps extract
            const float4* src = (const float4*)(img + (size_t)(rbase + (tno + 1) * TILE) * CI);
            r0 = src[tid]; r1 = src[tid + NTA]; r2 = src[tid + 2 * NTA];
        }
        __syncthreads();    // tile writes visible; also fences buf reuse (2-apart)
        const float* tl = tilebuf[tno & 1];
#pragma unroll
        for (int r = 0; r < 2; ++r) {
            int row = tid + r * NTA;
            float2 c = *(const float2*)(&tl[CI * row + 4]);
            float s = fmaxf(c.x, c.y);
            kreg[2 * tno + r] = (s > 0.5f) ? __float_as_uint(s) : 0u;
        }
    }

    // ---- bit-descend: find T with count(>=T) in [TOPK, CAND]
    unsigned int T = 0, cur = 0xFFFFFFFFu;
    for (int bit = 30; bit >= 0; --bit) {
        unsigned int T2 = T | (1u << bit);
        unsigned int c = 0;
#pragma unroll
        for (int u = 0; u < 16; ++u) c += (kreg[u] >= T2) ? 1u : 0u;
#pragma unroll
        for (int off = 32; off >= 1; off >>= 1) c += __shfl_down(c, off);
        if (lane == 0) redbuf[wid] = c;
        __syncthreads();
        if (tid == 0) {
            unsigned int tot = 0;
#pragma unroll
            for (int i = 0; i < 16; ++i) tot += redbuf[i];
            sh_cnt = tot;
        }
        __syncthreads();
        unsigned int tot = sh_cnt;
        if (tot >= TOPK) { T = T2; cur = tot; }
        if (cur >= TOPK && cur <= CAND && T != 0u) break;
    }
    if (T == 0u) T = 1u;   // fewer than 400 positives: take them all

    // ---- gather composites (key, ~idx) for keys >= T
    if (tid == 0) ccount = 0;
    cbuf[tid] = 0ull;
    __syncthreads();
#pragma unroll
    for (int u = 0; u < 16; ++u) {
        uint32_t key = kreg[u];
        if (key >= T) {
            unsigned int p = atomicAdd(&ccount, 1u);
            if (p < CAND) {
                unsigned int idx = (unsigned int)(rbase + (u >> 1) * TILE + tid + (u & 1) * NTA);
                cbuf[p] = ((unsigned long long)key << 32) |
                          (unsigned long long)(0xFFFFFFFFu - idx);
            }
        }
    }
    __syncthreads();

    // ---- bitonic sort 1024 desc (ties: lower idx first via ~idx low word)
    for (int kk = 2; kk <= CAND; kk <<= 1) {
        for (int j = kk >> 1; j > 0; j >>= 1) {
            int partner = tid ^ j;
            if (partner > tid) {
                unsigned long long a = cbuf[tid], c2 = cbuf[partner];
                if (((tid & kk) == 0) ? (a < c2) : (a > c2)) {
                    cbuf[tid] = c2; cbuf[partner] = a;
                }
            }
            __syncthreads();
        }
    }

    if (tid < TOPK) ws[(size_t)blk * TOPK + tid] = cbuf[tid];
}

// ---------------- Kernel B: merge halves + decode + NMS + output -----------
__global__ __launch_bounds__(NTB) void nms_kernel(
        const float* __restrict__ pred, const float* __restrict__ priors,
        const unsigned long long* __restrict__ ws, float* __restrict__ out) {
    const int b = blockIdx.x, tid = threadIdx.x;
    const float* img = pred + (size_t)b * (NN * CI);
    float* oimg = out + (size_t)b * KEEPK * 6;

    __shared__ unsigned long long lA[TOPK], lB[TOPK], cbuf[TOPK];
    __shared__ float4 cbox[TOPK];
    __shared__ float car[TOPK], csc[TOPK];
    __shared__ int clab[TOPK];
    __shared__ unsigned long long supm[TOPK * 7 + 8];
    __shared__ unsigned long long keepw[8];

    for (int i = tid; i < KEEPK * 6; i += NTB) oimg[i] = 0.0f;
    if (tid < TOPK) {
        lA[tid] = ws[(size_t)(2 * b) * TOPK + tid];
        lB[tid] = ws[(size_t)(2 * b + 1) * TOPK + tid];
        cbuf[tid] = 0ull;
    }
    if (tid < 8) keepw[tid] = 0ull;
    __syncthreads();

    // ---- merge-by-rank: union's t-th largest (composites unique; zeros invalid)
    if (tid < TOPK) {
        unsigned long long v = lA[tid];
        if (v) {
            int lo = 0, hi = TOPK;               // count in lB strictly > v
            while (lo < hi) { int mid = (lo + hi) >> 1; if (lB[mid] > v) lo = mid + 1; else hi = mid; }
            int rank = tid + lo;
            if (rank < TOPK) cbuf[rank] = v;
        }
        unsigned long long w = lB[tid];
        if (w) {
            int lo = 0, hi = TOPK;
            while (lo < hi) { int mid = (lo + hi) >> 1; if (lA[mid] > w) lo = mid + 1; else hi = mid; }
            int rank = tid + lo;
            if (rank < TOPK) cbuf[rank] = w;
        }
    }
    __syncthreads();

    // ---- decode candidates (reference float op order; no fma)
    if (tid < TOPK) {
        const int t = tid;
        unsigned long long c = cbuf[t];
        uint32_t key = (uint32_t)(c >> 32);
        uint32_t idx = 0xFFFFFFFFu - (uint32_t)(c & 0xFFFFFFFFull);
        int valid = (key != 0u) && (idx < NN);
        float x1 = 0.f, y1 = 0.f, x2 = 0.f, y2 = 0.f;
        int lab = 0;
        if (valid) {
            const float* p = img + (size_t)idx * CI;
            float l0 = p[0], l1 = p[1], l2 = p[2], l3 = p[3], c0 = p[4], c1 = p[5];
            const float* pr = priors + (size_t)idx * 4;
            float px = pr[0], py = pr[1], pw = pr[2], ph = pr[3];
            float cxv = __fadd_rn(px, __fmul_rn(__fmul_rn(l0, 0.1f), pw));
            float cyv = __fadd_rn(py, __fmul_rn(__fmul_rn(l1, 0.1f), ph));
            float ew = __fmul_rn(pw, expf(__fmul_rn(l2, 0.2f)));
            float eh = __fmul_rn(ph, expf(__fmul_rn(l3, 0.2f)));
            float hw = __fmul_rn(ew, 0.5f);
            float hh = __fmul_rn(eh, 0.5f);
            x1 = __fsub_rn(cxv, hw); y1 = __fsub_rn(cyv, hh);
            x2 = __fadd_rn(cxv, hw); y2 = __fadd_rn(cyv, hh);
            lab = (c1 > c0) ? 1 : 0;
        }
        cbox[t] = make_float4(x1, y1, x2, y2);
        csc[t] = __uint_as_float(key);
        car[t] = __fmul_rn(__fsub_rn(x2, x1), __fsub_rn(y2, y1));
        clab[t] = lab;
        if (valid) atomicOr(&keepw[t >> 6], 1ull << (t & 63));
    }
    __syncthreads();

    // ---- suppression bit-matrix, upper triangle only
    for (int task = tid; task < TOPK * 7; task += NTB) {
        int i = task / 7;
        int w4 = task - i * 7;
        int jbase = w4 << 6;
        int jmax = (TOPK - jbase < 64) ? (TOPK - jbase) : 64;
        int j0 = i + 1 - jbase; if (j0 < 0) j0 = 0;
        unsigned long long word = 0ull;
        if (j0 < jmax) {
            float4 bi = cbox[i]; float ai = car[i];
            for (int jj = j0; jj < jmax; jj++) {     // cbox[j]: broadcast reads
                int j = jbase + jj;
                float4 bj = cbox[j]; float aj = car[j];
                float iw = fmaxf(__fsub_rn(fminf(bi.z, bj.z), fmaxf(bi.x, bj.x)), 0.0f);
                float ih = fmaxf(__fsub_rn(fminf(bi.w, bj.w), fmaxf(bi.y, bj.y)), 0.0f);
                float inter = __fmul_rn(iw, ih);
                float denom = __fadd_rn(__fsub_rn(__fadd_rn(ai, aj), inter), 1e-12f);
                float iou = __fdiv_rn(inter, denom);
                if (iou > 0.5f) word |= (1ull << jj);
            }
        }
        supm[i * 7 + w4] = word;
    }
    __syncthreads();

    // ---- sequential resolve in one wave, keep bits in registers
    if (tid < 64) {
        int w = tid & 7;                    // lanes 0-6 own words; rest shadow
        unsigned long long kw = keepw[w];
        unsigned long long nxt = supm[w];
        for (int i = 0; i < TOPK; i++) {
            unsigned long long cur = nxt;
            int ni = (i + 1 < TOPK) ? (i + 1) : i;
            nxt = supm[ni * 7 + w];
            unsigned long long wv = __shfl(kw, i >> 6);
            if ((wv >> (i & 63)) & 1ull) kw &= ~cur;
        }
        if (tid < 7) keepw[tid] = kw;
    }
    __syncthreads();

    // ---- output: kept sorted ascending by (score, position), first 200 rows
    if (tid < TOPK) {
        const int t = tid;
        if ((keepw[t >> 6] >> (t & 63)) & 1ull) {
            float st = csc[t];
            int rank = 0;
            for (int j = 0; j < TOPK; j++) {
                bool kj = (keepw[j >> 6] >> (j & 63)) & 1ull;
                float sj = csc[j];
                if (kj && (sj < st || (sj == st && j < t))) rank++;
            }
            if (rank < KEEPK) {
                float4 bx = cbox[t];
                float* row = oimg + (size_t)rank * 6;
                row[0] = (float)clab[t];
                row[1] = st;
                row[2] = bx.x; row[3] = bx.y; row[4] = bx.z; row[5] = bx.w;
            }
        }
    }
}

extern "C" void kernel_launch(void* const* d_in, const int* in_sizes, int n_in,
                              void* d_out, int out_size, void* d_ws, size_t ws_size,
                              hipStream_t stream) {
    const float* pred = (const float*)d_in[0];     // (128, 32768, 6)
    const float* priors = (const float*)d_in[1];   // (32768, 4)
    float* out = (float*)d_out;                    // (128, 200, 6)
    unsigned long long* ws = (unsigned long long*)d_ws;   // 256*400*8 = 819 KB

    half_select_kernel<<<2 * BB, NTA, 0, stream>>>(pred, ws);
    nms_kernel<<<BB, NTB, 0, stream>>>(pred, priors, ws, out);
}